// Round 9
// baseline (125.270 us; speedup 1.0000x reference)
//
#include <hip/hip_runtime.h>
#include <math.h>

// Gaussian splatting forward rasterizer, MI355X.
// P=2048 gaussians, 128x128 image. Output: img (3*128*128 f32) ++ radii (P f32).
//
// R14: single NORMAL dispatch (R13's coop launch of 1024 blocks failed
// silently under graph capture -> outputs stayed zero). Deadlock-proof
// producer/consumer without coop:
//  - work-stealing prep: each block draws unit=fetch_add(g_unit); the first
//    64 blocks TO RUN do prep (32 gaussians each). Any resident subset
//    contains 64 claimants -> prep always completes -> gate always opens,
//    independent of dispatch order/occupancy (G16-safe).
//  - gate: poll g_done==64 with s_sleep; then raster.
//  - ALL cross-block traffic (records, culls, tickets, partials, gate) is
//    system-scope write-through/loads (R12's proven mechanism; no reliance
//    on intra-kernel L2 invalidation, no __threadfence L2 flushes).
//  - g_unit/g_done/g_passed are __device__ globals, self-resetting via
//    g_passed so each launch/rocprof-replay starts clean.
// Raster body, fold order, arithmetic verbatim R12 (95.6us, absmax 0.0).

#define IMG 128
#define NPIX (IMG * IMG)
#define GS 12        // record: px py ca cb cc op r g b r2 pad pad
#define SORT_N 2048
#define KCH 16
#define CHUNK (SORT_N / KCH)   // 128
#define NTILE 64
#define NPREP 64
#define PER_UNIT (SORT_N / NPREP)   // 32
#define GRID_TOTAL (NTILE * KCH)    // 1024

typedef unsigned long long u64;

__device__ unsigned int g_unit   = 0;   // prep work-stealing counter
__device__ unsigned int g_done   = 0;   // prep units completed
__device__ unsigned int g_passed = 0;   // blocks finished (for reset)

// -------- system-scope (write-through / L2-bypassing) helpers
__device__ __forceinline__ void sysStore4(float4* p, float4 v)
{
    union { float f[2]; u64 u; } lo, hi;
    lo.f[0] = v.x; lo.f[1] = v.y; hi.f[0] = v.z; hi.f[1] = v.w;
    u64* q = (u64*)p;
    __hip_atomic_store(q,     lo.u, __ATOMIC_RELAXED, __HIP_MEMORY_SCOPE_SYSTEM);
    __hip_atomic_store(q + 1, hi.u, __ATOMIC_RELAXED, __HIP_MEMORY_SCOPE_SYSTEM);
}
__device__ __forceinline__ float4 sysLoad4(const float4* p)
{
    const u64* q = (const u64*)p;
    u64 a = __hip_atomic_load(q,     __ATOMIC_RELAXED, __HIP_MEMORY_SCOPE_SYSTEM);
    u64 b = __hip_atomic_load(q + 1, __ATOMIC_RELAXED, __HIP_MEMORY_SCOPE_SYSTEM);
    union { u64 u; float f[2]; } lo, hi;
    lo.u = a; hi.u = b;
    return make_float4(lo.f[0], lo.f[1], hi.f[0], hi.f[1]);
}
__device__ __forceinline__ void sysStore2(float* p, float a, float b)
{
    union { float f[2]; u64 u; } v;
    v.f[0] = a; v.f[1] = b;
    __hip_atomic_store((u64*)p, v.u, __ATOMIC_RELAXED, __HIP_MEMORY_SCOPE_SYSTEM);
}

// ---------------------------------------------------------- projection chain
__device__ __forceinline__ void gproj(int i,
                                      const float* __restrict__ means,
                                      const float* __restrict__ rots,
                                      const float* __restrict__ scales,
                                      const float* __restrict__ vm,
                                      const float* __restrict__ pm,
                                      float& depth, bool& valid,
                                      float& px, float& py,
                                      float& ca, float& cb, float& cc,
                                      float& lam)
{
    const float W = (float)IMG, H = (float)IMG;
    const float tanfov = 0.5773502691896258f;        // tan(FOV/2)
    const float focal_x = W / (2.0f * tanfov);
    const float focal_y = H / (2.0f * tanfov);
    const float lim = 1.3f * tanfov;

    float mx = means[3 * i + 0], my = means[3 * i + 1], mz = means[3 * i + 2];

    float tx = vm[0] * mx + vm[1] * my + vm[2]  * mz + vm[3];
    float ty = vm[4] * mx + vm[5] * my + vm[6]  * mz + vm[7];
    float tz = vm[8] * mx + vm[9] * my + vm[10] * mz + vm[11];
    depth = tz;

    float ph0 = pm[0]  * mx + pm[1]  * my + pm[2]  * mz + pm[3];
    float ph1 = pm[4]  * mx + pm[5]  * my + pm[6]  * mz + pm[7];
    float pw  = pm[12] * mx + pm[13] * my + pm[14] * mz + pm[15];
    float rinv = 1.0f / (pw + 1e-7f);
    px = ((ph0 * rinv + 1.0f) * W - 1.0f) * 0.5f;
    py = ((ph1 * rinv + 1.0f) * H - 1.0f) * 0.5f;

    float qw = rots[4 * i + 0], qx = rots[4 * i + 1], qy = rots[4 * i + 2], qz = rots[4 * i + 3];
    float qn = sqrtf(qw * qw + qx * qx + qy * qy + qz * qz);
    qw /= qn; qx /= qn; qy /= qn; qz /= qn;
    float R00 = 1.0f - 2.0f * (qy * qy + qz * qz), R01 = 2.0f * (qx * qy - qw * qz), R02 = 2.0f * (qx * qz + qw * qy);
    float R10 = 2.0f * (qx * qy + qw * qz), R11 = 1.0f - 2.0f * (qx * qx + qz * qz), R12 = 2.0f * (qy * qz - qw * qx);
    float R20 = 2.0f * (qx * qz - qw * qy), R21 = 2.0f * (qy * qz + qw * qx), R22 = 1.0f - 2.0f * (qx * qx + qy * qy);

    float sx = scales[3 * i + 0], sy = scales[3 * i + 1], sz = scales[3 * i + 2];
    float M00 = R00 * sx, M01 = R01 * sy, M02 = R02 * sz;
    float M10 = R10 * sx, M11 = R11 * sy, M12 = R12 * sz;
    float M20 = R20 * sx, M21 = R21 * sy, M22 = R22 * sz;
    float S00 = M00 * M00 + M01 * M01 + M02 * M02;
    float S01 = M00 * M10 + M01 * M11 + M02 * M12;
    float S02 = M00 * M20 + M01 * M21 + M02 * M22;
    float S11 = M10 * M10 + M11 * M11 + M12 * M12;
    float S12 = M10 * M20 + M11 * M21 + M12 * M22;
    float S22 = M20 * M20 + M21 * M21 + M22 * M22;

    float txc = fminf(fmaxf(tx / tz, -lim), lim) * tz;
    float tyc = fminf(fmaxf(ty / tz, -lim), lim) * tz;
    float J00 = focal_x / tz, J02 = -focal_x * txc / (tz * tz);
    float J11 = focal_y / tz, J12 = -focal_y * tyc / (tz * tz);

    float T00 = J00 * vm[0] + J02 * vm[8];
    float T01 = J00 * vm[1] + J02 * vm[9];
    float T02 = J00 * vm[2] + J02 * vm[10];
    float T10 = J11 * vm[4] + J12 * vm[8];
    float T11 = J11 * vm[5] + J12 * vm[9];
    float T12 = J11 * vm[6] + J12 * vm[10];

    float U00 = T00 * S00 + T01 * S01 + T02 * S02;
    float U01 = T00 * S01 + T01 * S11 + T02 * S12;
    float U02 = T00 * S02 + T01 * S12 + T02 * S22;
    float U10 = T10 * S00 + T11 * S01 + T12 * S02;
    float U11 = T10 * S01 + T11 * S11 + T12 * S12;
    float U12 = T10 * S02 + T11 * S12 + T12 * S22;
    float C00 = U00 * T00 + U01 * T01 + U02 * T02;
    float C01 = U00 * T10 + U01 * T11 + U02 * T12;
    float C11 = U10 * T10 + U11 * T11 + U12 * T12;

    float a = C00 + 0.3f, b = C01, c = C11 + 0.3f;
    float det = a * c - b * b;
    valid = (depth > 0.2f) && (det > 0.0f);
    float det_s = valid ? det : 1.0f;
    ca = c / det_s; cb = -b / det_s; cc = a / det_s;

    float mid = 0.5f * (a + c);
    lam = mid + sqrtf(fmaxf(mid * mid - det, 0.1f));
}

// --------------------------------------------------- fused single dispatch
__global__ void __launch_bounds__(256, 4)
gsplat_one(const float* __restrict__ means,
           const float* __restrict__ feats,
           const float* __restrict__ ops,
           const float* __restrict__ scales,
           const float* __restrict__ rots,
           const float* __restrict__ vm,
           const float* __restrict__ pm,
           float* __restrict__ gS,
           float4* __restrict__ culls,
           float* __restrict__ radii_out,
           float4* __restrict__ part,
           unsigned int* __restrict__ tickets,
           float* __restrict__ img,
           int P)
{
    __shared__ unsigned int sk[SORT_N];      // 8 KB
    __shared__ int partial[256];             // 1 KB
    __shared__ unsigned int s_unit, s_old;
    int tid = threadIdx.x;
    int tile = blockIdx.x;                   // 0..63
    int kc   = blockIdx.y;                   // 0..15

    // ================= work-stealing prep claim
    if (tid == 0)
        s_unit = __hip_atomic_fetch_add(&g_unit, 1u,
                                        __ATOMIC_RELAXED, __HIP_MEMORY_SCOPE_SYSTEM);
    __syncthreads();
    unsigned int unit = s_unit;

    if (unit < NPREP) {
        // Phase A: all depth keys (valid == depth>0.2; det>0 always:
        // det = (C00+.3)(C11+.3)-C01^2 >= .3(C00+C11)+.09, cov2d PSD).
        #pragma unroll 2
        for (int j = tid; j < SORT_N; j += 256) {
            unsigned int key = 0xFFFFFFFFu;              // pad sorts last
            if (j < P) {
                float mx = means[3 * j + 0], my = means[3 * j + 1], mz = means[3 * j + 2];
                float tz = vm[8] * mx + vm[9] * my + vm[10] * mz + vm[11];
                key = (tz > 0.2f) ? __float_as_uint(tz) : 0x7f800000u;
            }
            sk[j] = key;
        }
        __syncthreads();

        // Phase B: stable rank of this unit's 32 gaussians (8 slices x 32).
        int g = tid & 31, s = tid >> 5;                  // s in [0,8)
        int i = (int)unit * PER_UNIT + g;
        bool act = (i < P);
        unsigned int ki = act ? sk[i] : 0u;

        const int SLICE = SORT_N / 8;                    // 256
        int j0 = s * SLICE;
        const uint4* sk4 = (const uint4*)(sk + j0);
        int r = 0;
        #pragma unroll 4
        for (int q = 0; q < SLICE / 4; ++q) {            // 64 iterations
            uint4 k = sk4[q];                            // wave-broadcast
            int j = j0 + 4 * q;
            r += (k.x < ki) || (k.x == ki && (j + 0) < i);
            r += (k.y < ki) || (k.y == ki && (j + 1) < i);
            r += (k.z < ki) || (k.z == ki && (j + 2) < i);
            r += (k.w < ki) || (k.w == ki && (j + 3) < i);
        }
        partial[tid] = r;
        __syncthreads();

        // Phase C: full record -> sorted slot (write-through).
        if (s == 0 && act) {                             // tid < 32
            int rank = 0;
            #pragma unroll
            for (int k = 0; k < 8; ++k) rank += partial[32 * k + g];

            float depth, px, py, ca, cb, cc, lam; bool valid;
            gproj(i, means, rots, scales, vm, pm, depth, valid, px, py, ca, cb, cc, lam);

            const float SH_C0 = 0.28209479177387814f;
            float colr = fmaxf(SH_C0 * feats[3 * i + 0] + 0.5f, 0.0f);
            float colg = fmaxf(SH_C0 * feats[3 * i + 1] + 0.5f, 0.0f);
            float colb = fmaxf(SH_C0 * feats[3 * i + 2] + 0.5f, 0.0f);

            float opv = ops[i];
            float r2;
            if (valid) {
                // alpha >= 1/255 requires d^2 <= 2*lam_max*ln(255*op)
                r2 = 2.0f * lam * __logf(255.0f * opv) * 1.02f + 0.5f;
            } else {
                px = 0.0f; py = 0.0f; ca = 0.0f; cb = 0.0f; cc = 0.0f;
                opv = 0.0f; r2 = -1.0f;                  // never composited
            }
            radii_out[i] = valid ? ceilf(3.0f * sqrtf(lam)) : 0.0f;

            float* dst = gS + (size_t)rank * GS;
            sysStore2(dst + 0, px, py);
            sysStore2(dst + 2, ca, cb);
            sysStore2(dst + 4, cc, opv);
            sysStore2(dst + 6, colr, colg);
            sysStore2(dst + 8, colb, r2);
            sysStore4(&culls[rank], make_float4(px, py, r2, 0.0f));
        }
        if (unit == 0 && tid < NTILE)                    // zero fold tickets
            __hip_atomic_store(&tickets[tid], 0u,
                               __ATOMIC_RELAXED, __HIP_MEMORY_SCOPE_SYSTEM);

        asm volatile("s_waitcnt vmcnt(0)" ::: "memory"); // stores at LLC
        __syncthreads();                                 // all waves drained
        if (tid == 0)
            __hip_atomic_fetch_add(&g_done, 1u,
                                   __ATOMIC_RELAXED, __HIP_MEMORY_SCOPE_SYSTEM);
    }

    // ================= gate: all 64 prep units done (opens because the
    // first 64 RUNNING blocks claimed the units -- no residency assumption)
    if (tid == 0) {
        while (__hip_atomic_load(&g_done, __ATOMIC_RELAXED,
                                 __HIP_MEMORY_SCOPE_SYSTEM) < NPREP)
            __builtin_amdgcn_s_sleep(8);
    }
    __syncthreads();

    // ================= raster (R12 body; system-scope reads) -------------
    int lx = tid & 15, ly = tid >> 4;
    int lane = tid & 63;
    int tilex = tile & 7, tiley = tile >> 3;
    int x = tilex * 16 + lx, y = tiley * 16 + ly;
    float gx = (float)x, gy = (float)y;
    float tx0 = (float)(tilex * 16), tx1 = (float)(tilex * 16 + 15);
    float ty0 = (float)(tiley * 16), ty1 = (float)(tiley * 16 + 15);

    int base = kc * CHUNK;
    int cnt = min(CHUNK, P - base);

    float T = 1.0f, cr = 0.0f, cg = 0.0f, cb = 0.0f;
    const float* Gp = gS + (size_t)base * GS;

    float4 cu0 = sysLoad4(&culls[base + lane]);
    float4 cu1 = sysLoad4(&culls[base + 64 + lane]);

    #pragma unroll
    for (int half = 0; half < 2; ++half) {
        int h = half * 64;
        float4 cu = (half == 0) ? cu0 : cu1;
        bool pred = false;
        if (h + lane < cnt) {
            float ddx = cu.x - fminf(fmaxf(cu.x, tx0), tx1);
            float ddy = cu.y - fminf(fmaxf(cu.y, ty0), ty1);
            pred = (ddx * ddx + ddy * ddy <= cu.z);
        }
        unsigned long long m = __ballot(pred);           // wave-uniform mask
        while (m) {
            int b0 = __builtin_ctzll(m); m &= m - 1;
            int n = 1, b1 = b0, b2 = b0, b3 = b0;
            if (m) { b1 = __builtin_ctzll(m); m &= m - 1; n = 2;
                if (m) { b2 = __builtin_ctzll(m); m &= m - 1; n = 3;
                    if (m) { b3 = __builtin_ctzll(m); m &= m - 1; n = 4; } } }

            const float4* R0 = (const float4*)(Gp + (size_t)(h + b0) * GS);
            const float4* R1 = (const float4*)(Gp + (size_t)(h + b1) * GS);
            const float4* R2 = (const float4*)(Gp + (size_t)(h + b2) * GS);
            const float4* R3 = (const float4*)(Gp + (size_t)(h + b3) * GS);
            float4 A0 = sysLoad4(R0 + 0), B0 = sysLoad4(R0 + 1), C0 = sysLoad4(R0 + 2);
            float4 A1 = sysLoad4(R1 + 0), B1 = sysLoad4(R1 + 1), C1 = sysLoad4(R1 + 2);
            float4 A2 = sysLoad4(R2 + 0), B2 = sysLoad4(R2 + 1), C2 = sysLoad4(R2 + 2);
            float4 A3 = sysLoad4(R3 + 0), B3 = sysLoad4(R3 + 1), C3 = sysLoad4(R3 + 2);

            float dx0 = gx - A0.x, dy0 = gy - A0.y;
            float p0 = -0.5f * (A0.z * dx0 * dx0 + B0.x * dy0 * dy0) - A0.w * dx0 * dy0;
            float a0 = fminf(0.99f, B0.y * __expf(fminf(p0, 0.0f)));
            a0 = (p0 > 0.0f) ? 0.0f : a0;
            a0 = (a0 < 0.00392156862745098f) ? 0.0f : a0;

            float dx1 = gx - A1.x, dy1 = gy - A1.y;
            float p1 = -0.5f * (A1.z * dx1 * dx1 + B1.x * dy1 * dy1) - A1.w * dx1 * dy1;
            float a1 = fminf(0.99f, B1.y * __expf(fminf(p1, 0.0f)));
            a1 = (p1 > 0.0f) ? 0.0f : a1;
            a1 = (a1 < 0.00392156862745098f) ? 0.0f : a1;

            float dx2 = gx - A2.x, dy2 = gy - A2.y;
            float p2 = -0.5f * (A2.z * dx2 * dx2 + B2.x * dy2 * dy2) - A2.w * dx2 * dy2;
            float a2 = fminf(0.99f, B2.y * __expf(fminf(p2, 0.0f)));
            a2 = (p2 > 0.0f) ? 0.0f : a2;
            a2 = (a2 < 0.00392156862745098f) ? 0.0f : a2;

            float dx3 = gx - A3.x, dy3 = gy - A3.y;
            float p3 = -0.5f * (A3.z * dx3 * dx3 + B3.x * dy3 * dy3) - A3.w * dx3 * dy3;
            float a3 = fminf(0.99f, B3.y * __expf(fminf(p3, 0.0f)));
            a3 = (p3 > 0.0f) ? 0.0f : a3;
            a3 = (a3 < 0.00392156862745098f) ? 0.0f : a3;

            float w;
            w = T * a0; cr = fmaf(w, B0.z, cr); cg = fmaf(w, B0.w, cg); cb = fmaf(w, C0.x, cb); T *= (1.0f - a0);
            if (n > 1) { w = T * a1; cr = fmaf(w, B1.z, cr); cg = fmaf(w, B1.w, cg); cb = fmaf(w, C1.x, cb); T *= (1.0f - a1); }
            if (n > 2) { w = T * a2; cr = fmaf(w, B2.z, cr); cg = fmaf(w, B2.w, cg); cb = fmaf(w, C2.x, cb); T *= (1.0f - a2); }
            if (n > 3) { w = T * a3; cr = fmaf(w, B3.z, cr); cg = fmaf(w, B3.w, cg); cb = fmaf(w, C3.x, cb); T *= (1.0f - a3); }
        }
    }

    // ---- write-through partial + ticket release (no cache flush)
    float4* slab = part + ((size_t)tile * KCH) * 256;
    sysStore4(&slab[kc * 256 + tid], make_float4(cr, cg, cb, T));
    asm volatile("s_waitcnt vmcnt(0)" ::: "memory");     // stores at LLC
    __syncthreads();                                     // whole block done
    if (tid == 0)
        s_old = __hip_atomic_fetch_add(&tickets[tile], 1u,
                                       __ATOMIC_RELAXED, __HIP_MEMORY_SCOPE_SYSTEM);
    __syncthreads();

    if (s_old == KCH - 1) {
        // All 16 partials at the coherent point; fold in exact chunk order.
        float4 v[8];
        float Tt = 1.0f, r = 0.0f, g = 0.0f, b = 0.0f;
        #pragma unroll
        for (int c = 0; c < 8; ++c) v[c] = sysLoad4(&slab[c * 256 + tid]);
        #pragma unroll
        for (int c = 0; c < 8; ++c) {
            r = fmaf(Tt, v[c].x, r);
            g = fmaf(Tt, v[c].y, g);
            b = fmaf(Tt, v[c].z, b);
            Tt *= v[c].w;
        }
        #pragma unroll
        for (int c = 0; c < 8; ++c) v[c] = sysLoad4(&slab[(8 + c) * 256 + tid]);
        #pragma unroll
        for (int c = 0; c < 8; ++c) {
            r = fmaf(Tt, v[c].x, r);
            g = fmaf(Tt, v[c].y, g);
            b = fmaf(Tt, v[c].z, b);
            Tt *= v[c].w;
        }
        int pix = y * IMG + x;
        img[pix]            = r + Tt;
        img[NPIX + pix]     = g + Tt;
        img[2 * NPIX + pix] = b + Tt;
    }

    // ================= self-reset of globals (next launch / rocprof replay)
    if (tid == 0) {
        unsigned int p = __hip_atomic_fetch_add(&g_passed, 1u,
                                                __ATOMIC_RELAXED, __HIP_MEMORY_SCOPE_SYSTEM);
        if (p == GRID_TOTAL - 1) {                       // last block out
            __hip_atomic_store(&g_unit,   0u, __ATOMIC_RELAXED, __HIP_MEMORY_SCOPE_SYSTEM);
            __hip_atomic_store(&g_done,   0u, __ATOMIC_RELAXED, __HIP_MEMORY_SCOPE_SYSTEM);
            __hip_atomic_store(&g_passed, 0u, __ATOMIC_RELAXED, __HIP_MEMORY_SCOPE_SYSTEM);
        }
    }
}

// ------------------------------------------------------------------ launch
extern "C" void kernel_launch(void* const* d_in, const int* in_sizes, int n_in,
                              void* d_out, int out_size, void* d_ws, size_t ws_size,
                              hipStream_t stream)
{
    const float* means  = (const float*)d_in[0];
    const float* feats  = (const float*)d_in[2];
    const float* ops    = (const float*)d_in[3];
    const float* scales = (const float*)d_in[4];
    const float* rots   = (const float*)d_in[5];
    const float* vm     = (const float*)d_in[6];
    const float* pm     = (const float*)d_in[7];

    int P = in_sizes[0] / 3;   // 2048

    float* img   = (float*)d_out;            // 3*128*128
    float* radii = (float*)d_out + 3 * NPIX; // P

    float*        gS      = (float*)d_ws;                         // 96 KB
    float4*       culls   = (float4*)(gS + (size_t)SORT_N * GS);  // 32 KB
    float4*       part    = culls + SORT_N;                       // 4 MB
    unsigned int* tickets = (unsigned int*)(part + (size_t)NTILE * KCH * 256);

    gsplat_one<<<dim3(NTILE, KCH), 256, 0, stream>>>(
        means, feats, ops, scales, rots, vm, pm,
        gS, culls, radii, part, tickets, img, P);
}

// Round 10
// 116.260 us; speedup vs baseline: 1.0775x; 1.0775x over previous
//
#include <hip/hip_runtime.h>
#include <math.h>

// Gaussian splatting forward rasterizer, MI355X.
// P=2048 gaussians, 128x128 image. Output: img (3*128*128 f32) ++ radii (P f32).
//
// R15: R14's single-dispatch skeleton (work-stealing prep -> s_sleep gate ->
// raster -> ticket fold; all proven correct, absmax 0.0) with its one perf
// bug fixed: R14 read records per-hit via SYSTEM-SCOPE ATOMIC LOADS =
// per-lane uncached non-coalescing LLC transactions (64x per wave-uniform
// read, same-line slice contention across the 64 tile-blocks sharing a
// chunk) -> 58us raster. Now each block stages its chunk's records+culls
// into LDS ONCE after the gate (384+128 float4 sysLoads, per-lane-DISTINCT
// addresses = coalesced & latency-hidden), and the ballot-cull + bit-loop
// run entirely from LDS (wave-uniform ds_read broadcasts). Partials/tickets/
// fold keep R12's write-through mechanism (per-lane-distinct addresses).
// LDS 17.4KB/block -> 4 blocks/CU intact. Arithmetic/order verbatim.

#define IMG 128
#define NPIX (IMG * IMG)
#define GS 12        // record: px py ca cb cc op r g b r2 pad pad
#define SORT_N 2048
#define KCH 16
#define CHUNK (SORT_N / KCH)   // 128
#define NTILE 64
#define NPREP 64
#define PER_UNIT (SORT_N / NPREP)   // 32
#define GRID_TOTAL (NTILE * KCH)    // 1024

typedef unsigned long long u64;

__device__ unsigned int g_unit   = 0;   // prep work-stealing counter
__device__ unsigned int g_done   = 0;   // prep units completed
__device__ unsigned int g_passed = 0;   // blocks finished (for reset)

// -------- system-scope (write-through / L2-bypassing) helpers
__device__ __forceinline__ void sysStore4(float4* p, float4 v)
{
    union { float f[2]; u64 u; } lo, hi;
    lo.f[0] = v.x; lo.f[1] = v.y; hi.f[0] = v.z; hi.f[1] = v.w;
    u64* q = (u64*)p;
    __hip_atomic_store(q,     lo.u, __ATOMIC_RELAXED, __HIP_MEMORY_SCOPE_SYSTEM);
    __hip_atomic_store(q + 1, hi.u, __ATOMIC_RELAXED, __HIP_MEMORY_SCOPE_SYSTEM);
}
__device__ __forceinline__ float4 sysLoad4(const float4* p)
{
    const u64* q = (const u64*)p;
    u64 a = __hip_atomic_load(q,     __ATOMIC_RELAXED, __HIP_MEMORY_SCOPE_SYSTEM);
    u64 b = __hip_atomic_load(q + 1, __ATOMIC_RELAXED, __HIP_MEMORY_SCOPE_SYSTEM);
    union { u64 u; float f[2]; } lo, hi;
    lo.u = a; hi.u = b;
    return make_float4(lo.f[0], lo.f[1], hi.f[0], hi.f[1]);
}
__device__ __forceinline__ void sysStore2(float* p, float a, float b)
{
    union { float f[2]; u64 u; } v;
    v.f[0] = a; v.f[1] = b;
    __hip_atomic_store((u64*)p, v.u, __ATOMIC_RELAXED, __HIP_MEMORY_SCOPE_SYSTEM);
}

// ---------------------------------------------------------- projection chain
__device__ __forceinline__ void gproj(int i,
                                      const float* __restrict__ means,
                                      const float* __restrict__ rots,
                                      const float* __restrict__ scales,
                                      const float* __restrict__ vm,
                                      const float* __restrict__ pm,
                                      float& depth, bool& valid,
                                      float& px, float& py,
                                      float& ca, float& cb, float& cc,
                                      float& lam)
{
    const float W = (float)IMG, H = (float)IMG;
    const float tanfov = 0.5773502691896258f;        // tan(FOV/2)
    const float focal_x = W / (2.0f * tanfov);
    const float focal_y = H / (2.0f * tanfov);
    const float lim = 1.3f * tanfov;

    float mx = means[3 * i + 0], my = means[3 * i + 1], mz = means[3 * i + 2];

    float tx = vm[0] * mx + vm[1] * my + vm[2]  * mz + vm[3];
    float ty = vm[4] * mx + vm[5] * my + vm[6]  * mz + vm[7];
    float tz = vm[8] * mx + vm[9] * my + vm[10] * mz + vm[11];
    depth = tz;

    float ph0 = pm[0]  * mx + pm[1]  * my + pm[2]  * mz + pm[3];
    float ph1 = pm[4]  * mx + pm[5]  * my + pm[6]  * mz + pm[7];
    float pw  = pm[12] * mx + pm[13] * my + pm[14] * mz + pm[15];
    float rinv = 1.0f / (pw + 1e-7f);
    px = ((ph0 * rinv + 1.0f) * W - 1.0f) * 0.5f;
    py = ((ph1 * rinv + 1.0f) * H - 1.0f) * 0.5f;

    float qw = rots[4 * i + 0], qx = rots[4 * i + 1], qy = rots[4 * i + 2], qz = rots[4 * i + 3];
    float qn = sqrtf(qw * qw + qx * qx + qy * qy + qz * qz);
    qw /= qn; qx /= qn; qy /= qn; qz /= qn;
    float R00 = 1.0f - 2.0f * (qy * qy + qz * qz), R01 = 2.0f * (qx * qy - qw * qz), R02 = 2.0f * (qx * qz + qw * qy);
    float R10 = 2.0f * (qx * qy + qw * qz), R11 = 1.0f - 2.0f * (qx * qx + qz * qz), R12 = 2.0f * (qy * qz - qw * qx);
    float R20 = 2.0f * (qx * qz - qw * qy), R21 = 2.0f * (qy * qz + qw * qx), R22 = 1.0f - 2.0f * (qx * qx + qy * qy);

    float sx = scales[3 * i + 0], sy = scales[3 * i + 1], sz = scales[3 * i + 2];
    float M00 = R00 * sx, M01 = R01 * sy, M02 = R02 * sz;
    float M10 = R10 * sx, M11 = R11 * sy, M12 = R12 * sz;
    float M20 = R20 * sx, M21 = R21 * sy, M22 = R22 * sz;
    float S00 = M00 * M00 + M01 * M01 + M02 * M02;
    float S01 = M00 * M10 + M01 * M11 + M02 * M12;
    float S02 = M00 * M20 + M01 * M21 + M02 * M22;
    float S11 = M10 * M10 + M11 * M11 + M12 * M12;
    float S12 = M10 * M20 + M11 * M21 + M12 * M22;
    float S22 = M20 * M20 + M21 * M21 + M22 * M22;

    float txc = fminf(fmaxf(tx / tz, -lim), lim) * tz;
    float tyc = fminf(fmaxf(ty / tz, -lim), lim) * tz;
    float J00 = focal_x / tz, J02 = -focal_x * txc / (tz * tz);
    float J11 = focal_y / tz, J12 = -focal_y * tyc / (tz * tz);

    float T00 = J00 * vm[0] + J02 * vm[8];
    float T01 = J00 * vm[1] + J02 * vm[9];
    float T02 = J00 * vm[2] + J02 * vm[10];
    float T10 = J11 * vm[4] + J12 * vm[8];
    float T11 = J11 * vm[5] + J12 * vm[9];
    float T12 = J11 * vm[6] + J12 * vm[10];

    float U00 = T00 * S00 + T01 * S01 + T02 * S02;
    float U01 = T00 * S01 + T01 * S11 + T02 * S12;
    float U02 = T00 * S02 + T01 * S12 + T02 * S22;
    float U10 = T10 * S00 + T11 * S01 + T12 * S02;
    float U11 = T10 * S01 + T11 * S11 + T12 * S12;
    float U12 = T10 * S02 + T11 * S12 + T12 * S22;
    float C00 = U00 * T00 + U01 * T01 + U02 * T02;
    float C01 = U00 * T10 + U01 * T11 + U02 * T12;
    float C11 = U10 * T10 + U11 * T11 + U12 * T12;

    float a = C00 + 0.3f, b = C01, c = C11 + 0.3f;
    float det = a * c - b * b;
    valid = (depth > 0.2f) && (det > 0.0f);
    float det_s = valid ? det : 1.0f;
    ca = c / det_s; cb = -b / det_s; cc = a / det_s;

    float mid = 0.5f * (a + c);
    lam = mid + sqrtf(fmaxf(mid * mid - det, 0.1f));
}

// --------------------------------------------------- fused single dispatch
__global__ void __launch_bounds__(256, 4)
gsplat_one(const float* __restrict__ means,
           const float* __restrict__ feats,
           const float* __restrict__ ops,
           const float* __restrict__ scales,
           const float* __restrict__ rots,
           const float* __restrict__ vm,
           const float* __restrict__ pm,
           float* __restrict__ gS,
           float4* __restrict__ culls,
           float* __restrict__ radii_out,
           float4* __restrict__ part,
           unsigned int* __restrict__ tickets,
           float* __restrict__ img,
           int P)
{
    __shared__ unsigned int sk[SORT_N];      // 8 KB (prep only)
    __shared__ int partial[256];             // 1 KB (prep only)
    __shared__ float srec[CHUNK * GS];       // 6 KB staged records
    __shared__ float4 scull[CHUNK];          // 2 KB staged culls
    __shared__ unsigned int s_unit, s_old;
    int tid = threadIdx.x;
    int tile = blockIdx.x;                   // 0..63
    int kc   = blockIdx.y;                   // 0..15

    // ================= work-stealing prep claim
    if (tid == 0)
        s_unit = __hip_atomic_fetch_add(&g_unit, 1u,
                                        __ATOMIC_RELAXED, __HIP_MEMORY_SCOPE_SYSTEM);
    __syncthreads();
    unsigned int unit = s_unit;

    if (unit < NPREP) {
        // Phase A: all depth keys (valid == depth>0.2; det>0 always:
        // det = (C00+.3)(C11+.3)-C01^2 >= .3(C00+C11)+.09, cov2d PSD).
        #pragma unroll 2
        for (int j = tid; j < SORT_N; j += 256) {
            unsigned int key = 0xFFFFFFFFu;              // pad sorts last
            if (j < P) {
                float mx = means[3 * j + 0], my = means[3 * j + 1], mz = means[3 * j + 2];
                float tz = vm[8] * mx + vm[9] * my + vm[10] * mz + vm[11];
                key = (tz > 0.2f) ? __float_as_uint(tz) : 0x7f800000u;
            }
            sk[j] = key;
        }
        __syncthreads();

        // Phase B: stable rank of this unit's 32 gaussians (8 slices x 32).
        int g = tid & 31, s = tid >> 5;                  // s in [0,8)
        int i = (int)unit * PER_UNIT + g;
        bool act = (i < P);
        unsigned int ki = act ? sk[i] : 0u;

        const int SLICE = SORT_N / 8;                    // 256
        int j0 = s * SLICE;
        const uint4* sk4 = (const uint4*)(sk + j0);
        int r = 0;
        #pragma unroll 4
        for (int q = 0; q < SLICE / 4; ++q) {            // 64 iterations
            uint4 k = sk4[q];                            // wave-broadcast
            int j = j0 + 4 * q;
            r += (k.x < ki) || (k.x == ki && (j + 0) < i);
            r += (k.y < ki) || (k.y == ki && (j + 1) < i);
            r += (k.z < ki) || (k.z == ki && (j + 2) < i);
            r += (k.w < ki) || (k.w == ki && (j + 3) < i);
        }
        partial[tid] = r;
        __syncthreads();

        // Phase C: full record -> sorted slot (write-through).
        if (s == 0 && act) {                             // tid < 32
            int rank = 0;
            #pragma unroll
            for (int k = 0; k < 8; ++k) rank += partial[32 * k + g];

            float depth, px, py, ca, cb, cc, lam; bool valid;
            gproj(i, means, rots, scales, vm, pm, depth, valid, px, py, ca, cb, cc, lam);

            const float SH_C0 = 0.28209479177387814f;
            float colr = fmaxf(SH_C0 * feats[3 * i + 0] + 0.5f, 0.0f);
            float colg = fmaxf(SH_C0 * feats[3 * i + 1] + 0.5f, 0.0f);
            float colb = fmaxf(SH_C0 * feats[3 * i + 2] + 0.5f, 0.0f);

            float opv = ops[i];
            float r2;
            if (valid) {
                // alpha >= 1/255 requires d^2 <= 2*lam_max*ln(255*op)
                r2 = 2.0f * lam * __logf(255.0f * opv) * 1.02f + 0.5f;
            } else {
                px = 0.0f; py = 0.0f; ca = 0.0f; cb = 0.0f; cc = 0.0f;
                opv = 0.0f; r2 = -1.0f;                  // never composited
            }
            radii_out[i] = valid ? ceilf(3.0f * sqrtf(lam)) : 0.0f;

            float* dst = gS + (size_t)rank * GS;
            sysStore2(dst + 0, px, py);
            sysStore2(dst + 2, ca, cb);
            sysStore2(dst + 4, cc, opv);
            sysStore2(dst + 6, colr, colg);
            sysStore2(dst + 8, colb, r2);
            sysStore4(&culls[rank], make_float4(px, py, r2, 0.0f));
        }
        if (unit == 0 && tid < NTILE)                    // zero fold tickets
            __hip_atomic_store(&tickets[tid], 0u,
                               __ATOMIC_RELAXED, __HIP_MEMORY_SCOPE_SYSTEM);

        asm volatile("s_waitcnt vmcnt(0)" ::: "memory"); // stores at LLC
        __syncthreads();                                 // all waves drained
        if (tid == 0)
            __hip_atomic_fetch_add(&g_done, 1u,
                                   __ATOMIC_RELAXED, __HIP_MEMORY_SCOPE_SYSTEM);
    }

    // ================= gate: all 64 prep units done (opens because the
    // first 64 RUNNING blocks claimed the units -- no residency assumption)
    if (tid == 0) {
        while (__hip_atomic_load(&g_done, __ATOMIC_RELAXED,
                                 __HIP_MEMORY_SCOPE_SYSTEM) < NPREP)
            __builtin_amdgcn_s_sleep(8);
    }
    __syncthreads();

    // ================= stage this chunk's records+culls into LDS (ONCE).
    // Per-lane-DISTINCT sysLoad4 addresses: coalesced, parallel, latency-
    // hidden. This is the only place uncached loads touch the records.
    int base = kc * CHUNK;
    {
        const float4* src = (const float4*)(gS + (size_t)base * GS);
        float4* dstl = (float4*)srec;
        #pragma unroll
        for (int j = tid; j < CHUNK * 3; j += 256)       // 384 float4
            dstl[j] = sysLoad4(&src[j]);
        for (int j = tid; j < CHUNK; j += 256)           // 128 float4
            scull[j] = sysLoad4(&culls[base + j]);
    }
    __syncthreads();

    // ================= raster (R12 body, LDS-sourced) --------------------
    int lx = tid & 15, ly = tid >> 4;
    int lane = tid & 63;
    int tilex = tile & 7, tiley = tile >> 3;
    int x = tilex * 16 + lx, y = tiley * 16 + ly;
    float gx = (float)x, gy = (float)y;
    float tx0 = (float)(tilex * 16), tx1 = (float)(tilex * 16 + 15);
    float ty0 = (float)(tiley * 16), ty1 = (float)(tiley * 16 + 15);

    int cnt = min(CHUNK, P - base);
    float T = 1.0f, cr = 0.0f, cg = 0.0f, cb = 0.0f;

    #pragma unroll
    for (int half = 0; half < 2; ++half) {
        int h = half * 64;
        float4 cu = scull[h + lane];
        bool pred = false;
        if (h + lane < cnt) {
            float ddx = cu.x - fminf(fmaxf(cu.x, tx0), tx1);
            float ddy = cu.y - fminf(fmaxf(cu.y, ty0), ty1);
            pred = (ddx * ddx + ddy * ddy <= cu.z);
        }
        unsigned long long m = __ballot(pred);           // wave-uniform mask
        while (m) {
            int b0 = __builtin_ctzll(m); m &= m - 1;
            int n = 1, b1 = b0, b2 = b0, b3 = b0;
            if (m) { b1 = __builtin_ctzll(m); m &= m - 1; n = 2;
                if (m) { b2 = __builtin_ctzll(m); m &= m - 1; n = 3;
                    if (m) { b3 = __builtin_ctzll(m); m &= m - 1; n = 4; } } }

            const float4* R0 = (const float4*)(srec + (size_t)(h + b0) * GS);
            const float4* R1 = (const float4*)(srec + (size_t)(h + b1) * GS);
            const float4* R2 = (const float4*)(srec + (size_t)(h + b2) * GS);
            const float4* R3 = (const float4*)(srec + (size_t)(h + b3) * GS);
            float4 A0 = R0[0], B0 = R0[1], C0 = R0[2];   // LDS broadcast
            float4 A1 = R1[0], B1 = R1[1], C1 = R1[2];
            float4 A2 = R2[0], B2 = R2[1], C2 = R2[2];
            float4 A3 = R3[0], B3 = R3[1], C3 = R3[2];

            float dx0 = gx - A0.x, dy0 = gy - A0.y;
            float p0 = -0.5f * (A0.z * dx0 * dx0 + B0.x * dy0 * dy0) - A0.w * dx0 * dy0;
            float a0 = fminf(0.99f, B0.y * __expf(fminf(p0, 0.0f)));
            a0 = (p0 > 0.0f) ? 0.0f : a0;
            a0 = (a0 < 0.00392156862745098f) ? 0.0f : a0;

            float dx1 = gx - A1.x, dy1 = gy - A1.y;
            float p1 = -0.5f * (A1.z * dx1 * dx1 + B1.x * dy1 * dy1) - A1.w * dx1 * dy1;
            float a1 = fminf(0.99f, B1.y * __expf(fminf(p1, 0.0f)));
            a1 = (p1 > 0.0f) ? 0.0f : a1;
            a1 = (a1 < 0.00392156862745098f) ? 0.0f : a1;

            float dx2 = gx - A2.x, dy2 = gy - A2.y;
            float p2 = -0.5f * (A2.z * dx2 * dx2 + B2.x * dy2 * dy2) - A2.w * dx2 * dy2;
            float a2 = fminf(0.99f, B2.y * __expf(fminf(p2, 0.0f)));
            a2 = (p2 > 0.0f) ? 0.0f : a2;
            a2 = (a2 < 0.00392156862745098f) ? 0.0f : a2;

            float dx3 = gx - A3.x, dy3 = gy - A3.y;
            float p3 = -0.5f * (A3.z * dx3 * dx3 + B3.x * dy3 * dy3) - A3.w * dx3 * dy3;
            float a3 = fminf(0.99f, B3.y * __expf(fminf(p3, 0.0f)));
            a3 = (p3 > 0.0f) ? 0.0f : a3;
            a3 = (a3 < 0.00392156862745098f) ? 0.0f : a3;

            float w;
            w = T * a0; cr = fmaf(w, B0.z, cr); cg = fmaf(w, B0.w, cg); cb = fmaf(w, C0.x, cb); T *= (1.0f - a0);
            if (n > 1) { w = T * a1; cr = fmaf(w, B1.z, cr); cg = fmaf(w, B1.w, cg); cb = fmaf(w, C1.x, cb); T *= (1.0f - a1); }
            if (n > 2) { w = T * a2; cr = fmaf(w, B2.z, cr); cg = fmaf(w, B2.w, cg); cb = fmaf(w, C2.x, cb); T *= (1.0f - a2); }
            if (n > 3) { w = T * a3; cr = fmaf(w, B3.z, cr); cg = fmaf(w, B3.w, cg); cb = fmaf(w, C3.x, cb); T *= (1.0f - a3); }
        }
    }

    // ---- write-through partial + ticket release (no cache flush)
    float4* slab = part + ((size_t)tile * KCH) * 256;
    sysStore4(&slab[kc * 256 + tid], make_float4(cr, cg, cb, T));
    asm volatile("s_waitcnt vmcnt(0)" ::: "memory");     // stores at LLC
    __syncthreads();                                     // whole block done
    if (tid == 0)
        s_old = __hip_atomic_fetch_add(&tickets[tile], 1u,
                                       __ATOMIC_RELAXED, __HIP_MEMORY_SCOPE_SYSTEM);
    __syncthreads();

    if (s_old == KCH - 1) {
        // All 16 partials at the coherent point; fold in exact chunk order.
        float4 v[8];
        float Tt = 1.0f, r = 0.0f, g = 0.0f, b = 0.0f;
        #pragma unroll
        for (int c = 0; c < 8; ++c) v[c] = sysLoad4(&slab[c * 256 + tid]);
        #pragma unroll
        for (int c = 0; c < 8; ++c) {
            r = fmaf(Tt, v[c].x, r);
            g = fmaf(Tt, v[c].y, g);
            b = fmaf(Tt, v[c].z, b);
            Tt *= v[c].w;
        }
        #pragma unroll
        for (int c = 0; c < 8; ++c) v[c] = sysLoad4(&slab[(8 + c) * 256 + tid]);
        #pragma unroll
        for (int c = 0; c < 8; ++c) {
            r = fmaf(Tt, v[c].x, r);
            g = fmaf(Tt, v[c].y, g);
            b = fmaf(Tt, v[c].z, b);
            Tt *= v[c].w;
        }
        int pix = y * IMG + x;
        img[pix]            = r + Tt;
        img[NPIX + pix]     = g + Tt;
        img[2 * NPIX + pix] = b + Tt;
    }

    // ================= self-reset of globals (next launch / rocprof replay)
    if (tid == 0) {
        unsigned int p = __hip_atomic_fetch_add(&g_passed, 1u,
                                                __ATOMIC_RELAXED, __HIP_MEMORY_SCOPE_SYSTEM);
        if (p == GRID_TOTAL - 1) {                       // last block out
            __hip_atomic_store(&g_unit,   0u, __ATOMIC_RELAXED, __HIP_MEMORY_SCOPE_SYSTEM);
            __hip_atomic_store(&g_done,   0u, __ATOMIC_RELAXED, __HIP_MEMORY_SCOPE_SYSTEM);
            __hip_atomic_store(&g_passed, 0u, __ATOMIC_RELAXED, __HIP_MEMORY_SCOPE_SYSTEM);
        }
    }
}

// ------------------------------------------------------------------ launch
extern "C" void kernel_launch(void* const* d_in, const int* in_sizes, int n_in,
                              void* d_out, int out_size, void* d_ws, size_t ws_size,
                              hipStream_t stream)
{
    const float* means  = (const float*)d_in[0];
    const float* feats  = (const float*)d_in[2];
    const float* ops    = (const float*)d_in[3];
    const float* scales = (const float*)d_in[4];
    const float* rots   = (const float*)d_in[5];
    const float* vm     = (const float*)d_in[6];
    const float* pm     = (const float*)d_in[7];

    int P = in_sizes[0] / 3;   // 2048

    float* img   = (float*)d_out;            // 3*128*128
    float* radii = (float*)d_out + 3 * NPIX; // P

    float*        gS      = (float*)d_ws;                         // 96 KB
    float4*       culls   = (float4*)(gS + (size_t)SORT_N * GS);  // 32 KB
    float4*       part    = culls + SORT_N;                       // 4 MB
    unsigned int* tickets = (unsigned int*)(part + (size_t)NTILE * KCH * 256);

    gsplat_one<<<dim3(NTILE, KCH), 256, 0, stream>>>(
        means, feats, ops, scales, rots, vm, pm,
        gS, culls, radii, part, tickets, img, P);
}

// Round 11
// 94.431 us; speedup vs baseline: 1.3266x; 1.2312x over previous
//
#include <hip/hip_runtime.h>
#include <math.h>

// Gaussian splatting forward rasterizer, MI355X.
// P=2048 gaussians, 128x128 image. Output: img (3*128*128 f32) ++ radii (P f32).
//
// R16 == R12 verbatim (best verified: 95.6us, absmax 0.0).
// Structure: TWO dispatches.
//   1) prep_rank_scatter (32 blocks x 512 thr): depth-only keys, 8-slice
//      stable rank, full record scatter to sorted slots + compact culls.
//   2) raster_fused (64 tiles x 16 chunks): ballot cull + 4-wide ILP
//      bit-loop; partials written WRITE-THROUGH (system-scope relaxed
//      stores -> LLC, no L2 flush), vmcnt(0), per-tile ticket fetch_add;
//      the block drawing ticket 15 folds all 16 partials in chunk order.
// Why not more fusion (all measured, all worse): grid.sync = 65us/barrier
// (R7); per-block __threadfence = ~0.7us x blocks (R10, 93us); intra-kernel
// atomic gate + self-reset = ~2048 same-address LLC RMWs ~ 30-40us
// (R14/R15). A kernel boundary costs ~3-5us -- two dispatches win.
// Fixed floor: harness poisons the 256MiB workspace twice per iteration
// (2 x ~40us fills at 85% HBM peak) -- not controllable from the kernel.

#define IMG 128
#define NPIX (IMG * IMG)
#define GS 12        // record: px py ca cb cc op r g b r2 pad pad
#define SORT_N 2048
#define KCH 16
#define CHUNK (SORT_N / KCH)   // 128
#define NTILE 64

typedef unsigned long long u64;

// -------- system-scope (write-through, L2-bypassing) 16B helpers
__device__ __forceinline__ void sysStore4(float4* p, float4 v)
{
    union { float f[2]; u64 u; } lo, hi;
    lo.f[0] = v.x; lo.f[1] = v.y; hi.f[0] = v.z; hi.f[1] = v.w;
    u64* q = (u64*)p;
    __hip_atomic_store(q,     lo.u, __ATOMIC_RELAXED, __HIP_MEMORY_SCOPE_SYSTEM);
    __hip_atomic_store(q + 1, hi.u, __ATOMIC_RELAXED, __HIP_MEMORY_SCOPE_SYSTEM);
}
__device__ __forceinline__ float4 sysLoad4(const float4* p)
{
    const u64* q = (const u64*)p;
    u64 a = __hip_atomic_load(q,     __ATOMIC_RELAXED, __HIP_MEMORY_SCOPE_SYSTEM);
    u64 b = __hip_atomic_load(q + 1, __ATOMIC_RELAXED, __HIP_MEMORY_SCOPE_SYSTEM);
    union { u64 u; float f[2]; } lo, hi;
    lo.u = a; hi.u = b;
    return make_float4(lo.f[0], lo.f[1], hi.f[0], hi.f[1]);
}

// ---------------------------------------------------------- projection chain
__device__ __forceinline__ void gproj(int i,
                                      const float* __restrict__ means,
                                      const float* __restrict__ rots,
                                      const float* __restrict__ scales,
                                      const float* __restrict__ vm,
                                      const float* __restrict__ pm,
                                      float& depth, bool& valid,
                                      float& px, float& py,
                                      float& ca, float& cb, float& cc,
                                      float& lam)
{
    const float W = (float)IMG, H = (float)IMG;
    const float tanfov = 0.5773502691896258f;        // tan(FOV/2)
    const float focal_x = W / (2.0f * tanfov);
    const float focal_y = H / (2.0f * tanfov);
    const float lim = 1.3f * tanfov;

    float mx = means[3 * i + 0], my = means[3 * i + 1], mz = means[3 * i + 2];

    float tx = vm[0] * mx + vm[1] * my + vm[2]  * mz + vm[3];
    float ty = vm[4] * mx + vm[5] * my + vm[6]  * mz + vm[7];
    float tz = vm[8] * mx + vm[9] * my + vm[10] * mz + vm[11];
    depth = tz;

    float ph0 = pm[0]  * mx + pm[1]  * my + pm[2]  * mz + pm[3];
    float ph1 = pm[4]  * mx + pm[5]  * my + pm[6]  * mz + pm[7];
    float pw  = pm[12] * mx + pm[13] * my + pm[14] * mz + pm[15];
    float rinv = 1.0f / (pw + 1e-7f);
    px = ((ph0 * rinv + 1.0f) * W - 1.0f) * 0.5f;
    py = ((ph1 * rinv + 1.0f) * H - 1.0f) * 0.5f;

    float qw = rots[4 * i + 0], qx = rots[4 * i + 1], qy = rots[4 * i + 2], qz = rots[4 * i + 3];
    float qn = sqrtf(qw * qw + qx * qx + qy * qy + qz * qz);
    qw /= qn; qx /= qn; qy /= qn; qz /= qn;
    float R00 = 1.0f - 2.0f * (qy * qy + qz * qz), R01 = 2.0f * (qx * qy - qw * qz), R02 = 2.0f * (qx * qz + qw * qy);
    float R10 = 2.0f * (qx * qy + qw * qz), R11 = 1.0f - 2.0f * (qx * qx + qz * qz), R12 = 2.0f * (qy * qz - qw * qx);
    float R20 = 2.0f * (qx * qz - qw * qy), R21 = 2.0f * (qy * qz + qw * qx), R22 = 1.0f - 2.0f * (qx * qx + qy * qy);

    float sx = scales[3 * i + 0], sy = scales[3 * i + 1], sz = scales[3 * i + 2];
    float M00 = R00 * sx, M01 = R01 * sy, M02 = R02 * sz;
    float M10 = R10 * sx, M11 = R11 * sy, M12 = R12 * sz;
    float M20 = R20 * sx, M21 = R21 * sy, M22 = R22 * sz;
    float S00 = M00 * M00 + M01 * M01 + M02 * M02;
    float S01 = M00 * M10 + M01 * M11 + M02 * M12;
    float S02 = M00 * M20 + M01 * M21 + M02 * M22;
    float S11 = M10 * M10 + M11 * M11 + M12 * M12;
    float S12 = M10 * M20 + M11 * M21 + M12 * M22;
    float S22 = M20 * M20 + M21 * M21 + M22 * M22;

    float txc = fminf(fmaxf(tx / tz, -lim), lim) * tz;
    float tyc = fminf(fmaxf(ty / tz, -lim), lim) * tz;
    float J00 = focal_x / tz, J02 = -focal_x * txc / (tz * tz);
    float J11 = focal_y / tz, J12 = -focal_y * tyc / (tz * tz);

    float T00 = J00 * vm[0] + J02 * vm[8];
    float T01 = J00 * vm[1] + J02 * vm[9];
    float T02 = J00 * vm[2] + J02 * vm[10];
    float T10 = J11 * vm[4] + J12 * vm[8];
    float T11 = J11 * vm[5] + J12 * vm[9];
    float T12 = J11 * vm[6] + J12 * vm[10];

    float U00 = T00 * S00 + T01 * S01 + T02 * S02;
    float U01 = T00 * S01 + T01 * S11 + T02 * S12;
    float U02 = T00 * S02 + T01 * S12 + T02 * S22;
    float U10 = T10 * S00 + T11 * S01 + T12 * S02;
    float U11 = T10 * S01 + T11 * S11 + T12 * S12;
    float U12 = T10 * S02 + T11 * S12 + T12 * S22;
    float C00 = U00 * T00 + U01 * T01 + U02 * T02;
    float C01 = U00 * T10 + U01 * T11 + U02 * T12;
    float C11 = U10 * T10 + U11 * T11 + U12 * T12;

    float a = C00 + 0.3f, b = C01, c = C11 + 0.3f;
    float det = a * c - b * b;
    valid = (depth > 0.2f) && (det > 0.0f);
    float det_s = valid ? det : 1.0f;
    ca = c / det_s; cb = -b / det_s; cc = a / det_s;

    float mid = 0.5f * (a + c);
    lam = mid + sqrtf(fmaxf(mid * mid - det, 0.1f));
}

// ------------------------------------------- fused preprocess + rank + scatter
// 512 threads: 8 key-slices x 64 gaussians -> Phase B is 64 uint4 iterations.
__global__ void __launch_bounds__(512)
gsplat_prep_rank_scatter(const float* __restrict__ means,
                         const float* __restrict__ feats,
                         const float* __restrict__ ops,
                         const float* __restrict__ scales,
                         const float* __restrict__ rots,
                         const float* __restrict__ vm,
                         const float* __restrict__ pm,
                         float* __restrict__ gS,
                         float4* __restrict__ culls,
                         float* __restrict__ radii_out,
                         unsigned int* __restrict__ tickets,
                         int P)
{
    __shared__ unsigned int sk[SORT_N];
    __shared__ int partial[512];
    int tid = threadIdx.x;

    // Zero the raster's per-tile tickets (kernel boundary gives visibility).
    if (blockIdx.x == 0 && tid < NTILE) tickets[tid] = 0u;

    // Phase A: depth-only sort keys. valid == depth>0.2 (det>0 always:
    // det = (C00+.3)(C11+.3)-C01^2 >= .3(C00+C11)+.09, cov2d PSD; margin
    // ~1e3 vs fp32 error ~1e-3 -- holds in the reference too).
    #pragma unroll 2
    for (int j = tid; j < SORT_N; j += 512) {
        unsigned int key = 0xFFFFFFFFu;                  // pad sorts last
        if (j < P) {
            float mx = means[3 * j + 0], my = means[3 * j + 1], mz = means[3 * j + 2];
            float tz = vm[8] * mx + vm[9] * my + vm[10] * mz + vm[11];
            key = (tz > 0.2f) ? __float_as_uint(tz) : 0x7f800000u; // +inf invalid
        }
        sk[j] = key;
    }
    __syncthreads();

    // Phase B: stable rank for this block's 64 gaussians (8 key-slices x 64).
    int g = tid & 63, s = tid >> 6;                      // s in [0,8)
    int i = blockIdx.x * 64 + g;
    bool act = (i < P);
    unsigned int ki = act ? sk[i] : 0u;

    const int SLICE = SORT_N / 8;                        // 256
    int j0 = s * SLICE;
    const uint4* sk4 = (const uint4*)(sk + j0);
    int r = 0;
    #pragma unroll 4
    for (int q = 0; q < SLICE / 4; ++q) {                // 64 iterations
        uint4 k = sk4[q];                                // wave-broadcast
        int j = j0 + 4 * q;
        r += (k.x < ki) || (k.x == ki && (j + 0) < i);
        r += (k.y < ki) || (k.y == ki && (j + 1) < i);
        r += (k.z < ki) || (k.z == ki && (j + 2) < i);
        r += (k.w < ki) || (k.w == ki && (j + 3) < i);
    }
    partial[tid] = r;
    __syncthreads();

    // Phase C: full record for own gaussian -> sorted slot; radii in orig order.
    if (s == 0 && act) {
        int rank = 0;
        #pragma unroll
        for (int k = 0; k < 8; ++k) rank += partial[64 * k + g];

        float depth, px, py, ca, cb, cc, lam; bool valid;
        gproj(i, means, rots, scales, vm, pm, depth, valid, px, py, ca, cb, cc, lam);

        const float SH_C0 = 0.28209479177387814f;
        float colr = fmaxf(SH_C0 * feats[3 * i + 0] + 0.5f, 0.0f);
        float colg = fmaxf(SH_C0 * feats[3 * i + 1] + 0.5f, 0.0f);
        float colb = fmaxf(SH_C0 * feats[3 * i + 2] + 0.5f, 0.0f);

        float opv = ops[i];
        float r2;
        if (valid) {
            // alpha >= 1/255 requires d^2 <= 2*lam_max*ln(255*op) (exact bound)
            r2 = 2.0f * lam * __logf(255.0f * opv) * 1.02f + 0.5f;
        } else {
            px = 0.0f; py = 0.0f; ca = 0.0f; cb = 0.0f; cc = 0.0f;
            opv = 0.0f; r2 = -1.0f;                      // never composited
        }
        radii_out[i] = valid ? ceilf(3.0f * sqrtf(lam)) : 0.0f;

        float4* dst = (float4*)(gS + (size_t)rank * GS);
        dst[0] = make_float4(px, py, ca, cb);
        dst[1] = make_float4(cc, opv, colr, colg);
        dst[2] = make_float4(colb, r2, 0.0f, 0.0f);
        culls[rank] = make_float4(px, py, r2, 0.0f);     // compact cull record
    }
}

// ------------------------------------------------- raster + fused combine
// Block = (tile, chunk): 64 tiles x KCH=16 chunks = 1024 blocks (4/CU).
// R9's ballot cull + 4-wide unrolled bit-loop. Epilogue: partial written
// WRITE-THROUGH (system-scope relaxed stores, no L2 flush), s_waitcnt
// vmcnt(0), ticket fetch_add; block drawing ticket KCH-1 folds all 16
// partials (system-scope loads from LLC) in exact chunk order.
__global__ void __launch_bounds__(256, 4)
gsplat_raster_fused(const float* __restrict__ gS,
                    const float4* __restrict__ culls,
                    int P, float4* __restrict__ part,
                    unsigned int* __restrict__ tickets,
                    float* __restrict__ img)
{
    int tid = threadIdx.x;
    int lx = tid & 15, ly = tid >> 4;
    int lane = tid & 63;
    int tile = blockIdx.x;
    int kc = blockIdx.y;
    int tilex = tile & 7, tiley = tile >> 3;
    int x = tilex * 16 + lx, y = tiley * 16 + ly;
    float gx = (float)x, gy = (float)y;
    float tx0 = (float)(tilex * 16), tx1 = (float)(tilex * 16 + 15);
    float ty0 = (float)(tiley * 16), ty1 = (float)(tiley * 16 + 15);

    int base = kc * CHUNK;
    int cnt = min(CHUNK, P - base);

    float T = 1.0f, cr = 0.0f, cg = 0.0f, cb = 0.0f;
    const float* Gp = gS + (size_t)base * GS;

    // Both cull loads issue immediately (independent).
    float4 cu0 = culls[base + lane];
    float4 cu1 = culls[base + 64 + lane];

    #pragma unroll
    for (int half = 0; half < 2; ++half) {
        int h = half * 64;
        float4 cu = (half == 0) ? cu0 : cu1;
        bool pred = false;
        if (h + lane < cnt) {
            float ddx = cu.x - fminf(fmaxf(cu.x, tx0), tx1);
            float ddy = cu.y - fminf(fmaxf(cu.y, ty0), ty1);
            pred = (ddx * ddx + ddy * ddy <= cu.z);
        }
        unsigned long long m = __ballot(pred);           // wave-uniform mask
        while (m) {
            int b0 = __builtin_ctzll(m); m &= m - 1;
            int n = 1, b1 = b0, b2 = b0, b3 = b0;
            if (m) { b1 = __builtin_ctzll(m); m &= m - 1; n = 2;
                if (m) { b2 = __builtin_ctzll(m); m &= m - 1; n = 3;
                    if (m) { b3 = __builtin_ctzll(m); m &= m - 1; n = 4; } } }

            const float4* R0 = (const float4*)(Gp + (size_t)(h + b0) * GS);
            const float4* R1 = (const float4*)(Gp + (size_t)(h + b1) * GS);
            const float4* R2 = (const float4*)(Gp + (size_t)(h + b2) * GS);
            const float4* R3 = (const float4*)(Gp + (size_t)(h + b3) * GS);
            float4 A0 = R0[0], B0 = R0[1], C0 = R0[2];
            float4 A1 = R1[0], B1 = R1[1], C1 = R1[2];
            float4 A2 = R2[0], B2 = R2[1], C2 = R2[2];
            float4 A3 = R3[0], B3 = R3[1], C3 = R3[2];

            float dx0 = gx - A0.x, dy0 = gy - A0.y;
            float p0 = -0.5f * (A0.z * dx0 * dx0 + B0.x * dy0 * dy0) - A0.w * dx0 * dy0;
            float a0 = fminf(0.99f, B0.y * __expf(fminf(p0, 0.0f)));
            a0 = (p0 > 0.0f) ? 0.0f : a0;
            a0 = (a0 < 0.00392156862745098f) ? 0.0f : a0;

            float dx1 = gx - A1.x, dy1 = gy - A1.y;
            float p1 = -0.5f * (A1.z * dx1 * dx1 + B1.x * dy1 * dy1) - A1.w * dx1 * dy1;
            float a1 = fminf(0.99f, B1.y * __expf(fminf(p1, 0.0f)));
            a1 = (p1 > 0.0f) ? 0.0f : a1;
            a1 = (a1 < 0.00392156862745098f) ? 0.0f : a1;

            float dx2 = gx - A2.x, dy2 = gy - A2.y;
            float p2 = -0.5f * (A2.z * dx2 * dx2 + B2.x * dy2 * dy2) - A2.w * dx2 * dy2;
            float a2 = fminf(0.99f, B2.y * __expf(fminf(p2, 0.0f)));
            a2 = (p2 > 0.0f) ? 0.0f : a2;
            a2 = (a2 < 0.00392156862745098f) ? 0.0f : a2;

            float dx3 = gx - A3.x, dy3 = gy - A3.y;
            float p3 = -0.5f * (A3.z * dx3 * dx3 + B3.x * dy3 * dy3) - A3.w * dx3 * dy3;
            float a3 = fminf(0.99f, B3.y * __expf(fminf(p3, 0.0f)));
            a3 = (p3 > 0.0f) ? 0.0f : a3;
            a3 = (a3 < 0.00392156862745098f) ? 0.0f : a3;

            float w;
            w = T * a0; cr = fmaf(w, B0.z, cr); cg = fmaf(w, B0.w, cg); cb = fmaf(w, C0.x, cb); T *= (1.0f - a0);
            if (n > 1) { w = T * a1; cr = fmaf(w, B1.z, cr); cg = fmaf(w, B1.w, cg); cb = fmaf(w, C1.x, cb); T *= (1.0f - a1); }
            if (n > 2) { w = T * a2; cr = fmaf(w, B2.z, cr); cg = fmaf(w, B2.w, cg); cb = fmaf(w, C2.x, cb); T *= (1.0f - a2); }
            if (n > 3) { w = T * a3; cr = fmaf(w, B3.z, cr); cg = fmaf(w, B3.w, cg); cb = fmaf(w, C3.x, cb); T *= (1.0f - a3); }
        }
    }

    // ---- write-through partial + ticket release (no cache flush)
    float4* slab = part + ((size_t)tile * KCH) * 256;
    sysStore4(&slab[kc * 256 + tid], make_float4(cr, cg, cb, T));
    asm volatile("s_waitcnt vmcnt(0)" ::: "memory");     // stores at LLC
    __syncthreads();                                     // whole block done
    __shared__ unsigned int s_old;
    if (tid == 0)
        s_old = __hip_atomic_fetch_add(&tickets[tile], 1u,
                                       __ATOMIC_RELAXED, __HIP_MEMORY_SCOPE_SYSTEM);
    __syncthreads();

    if (s_old == KCH - 1) {
        // All 16 partials are at the coherent point; fold in chunk order.
        float4 v[8];
        float Tt = 1.0f, r = 0.0f, g = 0.0f, b = 0.0f;
        #pragma unroll
        for (int c = 0; c < 8; ++c) v[c] = sysLoad4(&slab[c * 256 + tid]);
        #pragma unroll
        for (int c = 0; c < 8; ++c) {
            r = fmaf(Tt, v[c].x, r);
            g = fmaf(Tt, v[c].y, g);
            b = fmaf(Tt, v[c].z, b);
            Tt *= v[c].w;
        }
        #pragma unroll
        for (int c = 0; c < 8; ++c) v[c] = sysLoad4(&slab[(8 + c) * 256 + tid]);
        #pragma unroll
        for (int c = 0; c < 8; ++c) {
            r = fmaf(Tt, v[c].x, r);
            g = fmaf(Tt, v[c].y, g);
            b = fmaf(Tt, v[c].z, b);
            Tt *= v[c].w;
        }
        int pix = y * IMG + x;
        img[pix]            = r + Tt;
        img[NPIX + pix]     = g + Tt;
        img[2 * NPIX + pix] = b + Tt;
    }
}

// ------------------------------------------------------------------ launch
extern "C" void kernel_launch(void* const* d_in, const int* in_sizes, int n_in,
                              void* d_out, int out_size, void* d_ws, size_t ws_size,
                              hipStream_t stream)
{
    const float* means  = (const float*)d_in[0];
    const float* feats  = (const float*)d_in[2];
    const float* ops    = (const float*)d_in[3];
    const float* scales = (const float*)d_in[4];
    const float* rots   = (const float*)d_in[5];
    const float* vm     = (const float*)d_in[6];
    const float* pm     = (const float*)d_in[7];

    int P = in_sizes[0] / 3;   // 2048

    float* img   = (float*)d_out;            // 3*128*128
    float* radii = (float*)d_out + 3 * NPIX; // P

    float*        gS      = (float*)d_ws;                         // 96 KB
    float4*       culls   = (float4*)(gS + (size_t)SORT_N * GS);  // 32 KB
    float4*       part    = culls + SORT_N;                       // 4 MB
    unsigned int* tickets = (unsigned int*)(part + (size_t)NTILE * KCH * 256);

    gsplat_prep_rank_scatter<<<(P + 63) / 64, 512, 0, stream>>>(
        means, feats, ops, scales, rots, vm, pm, gS, culls, radii, tickets, P);

    gsplat_raster_fused<<<dim3(NTILE, KCH), 256, 0, stream>>>(
        gS, culls, P, part, tickets, img);
}